// Round 3
// baseline (763.643 us; speedup 1.0000x reference)
//
#include <hip/hip_runtime.h>

#define F 256
#define TWO_F 512
#define BM 128
#define BN 64
#define BK 64
#define NITER 7      // m-strips per gemm block
#define NBKT 392     // edge src buckets = ceil(50000/128)

typedef __attribute__((ext_vector_type(8))) short short8;
typedef __attribute__((ext_vector_type(4))) float float4v;

// ---------- bf16 helpers ----------
static __device__ __forceinline__ unsigned short f2bf(float f) {
    unsigned u = __float_as_uint(f);
    u += 0x7FFFu + ((u >> 16) & 1u);
    return (unsigned short)(u >> 16);
}
static __device__ __forceinline__ unsigned pack2(float lo, float hi) {
    unsigned a = __float_as_uint(lo) + 0x8000u;
    unsigned b = __float_as_uint(hi) + 0x8000u;
    return __builtin_amdgcn_perm(b, a, 0x07060302u);
}
static __device__ __forceinline__ float blo(unsigned u) { return __uint_as_float(u << 16); }
static __device__ __forceinline__ float rawf(unsigned u) { return __uint_as_float(u); }

// ---------- kernel 1 (merged prep): h fp32->hb bf16 and W1 fp32->Wb bf16, both k-rotated ----------
__global__ __launch_bounds__(256) void prep_kernel(
    const float* __restrict__ h, const float* __restrict__ W1,
    unsigned short* __restrict__ hb, unsigned short* __restrict__ Wb, int M)
{
    int i = blockIdx.x * blockDim.x + threadIdx.x;
    if (i < M * 128) {                       // h part: one bf16 pair per thread
        int m = i >> 7;
        int kp = (i & 127) * 2;
        float2 v = *(const float2*)(h + (size_t)m * F + kp);
        unsigned pk = pack2(v.x, v.y);
        int ksw = ((kp & 63) + (m & 7) * 8) & 63;
        *(unsigned*)(hb + (size_t)m * F + (kp & ~63) + ksw) = pk;
    }
    if (i < TWO_F * F) {                     // W part
        int n = i >> 8;
        int k = i & 255;
        float v = W1[(n & 255) * TWO_F + ((n >> 8) << 8) + k];
        int kin_sw = ((k & 63) + (n & 7) * 8) & 63;
        Wb[n * F + (k & ~63) + kin_sw] = f2bf(v);
    }
}

// ---------- kernel 2: C[m][n] = sum_k hb[m][k]*Wb[n][k] (+b1 for n<256), bf16 out ----------
// Restructured vs r2: W panel (64x256, 32KB) staged in LDS ONCE per block and reused across
// NITER=7 m-strips (kills per-block 256KB Wb L2 re-reads -> was thrashing private 4MB L2s).
// sA double-buffered (2x16KB). LDS 64KB -> 2 blocks/CU. Grid 56x8=448; mapping keeps all 8
// n-blocks of one m-group on one XCD (ib&7 == bxg&7) so hb strips are L2-shared.
__global__ __launch_bounds__(256, 2) void gemm_kernel(
    const unsigned short* __restrict__ hb, const unsigned short* __restrict__ Wb,
    const float* __restrict__ b1v, unsigned short* __restrict__ C, int M)
{
    __shared__ unsigned short sB[BN * F];        // 32 KB, full-K W panel (persistent)
    __shared__ unsigned short sA[2][BM * BK];    // 2 x 16 KB, double-buffered A tile

    const int ib  = blockIdx.x;
    const int r8  = ib & 7;
    const int t   = ib >> 3;             // 0..55
    const int bxg = (t % 7) * 8 + r8;    // 0..55 (bijective; low 3 bits == r8 -> same XCD)
    const int by  = t / 7;               // 0..7
    const int bn  = by * BN;

    const int tid  = threadIdx.x;
    const int lane = tid & 63;
    const int wid  = tid >> 6;
    const int st_r = lane >> 3;
    const int st_k = (lane & 7) * 8;
    const int quad = lane >> 4;
    const int l15  = lane & 15;
    const int rot  = (l15 & 7) * 8;

    // stage the whole W panel once: wave wid covers rows wid*16..+15 (8 issues x 2 rows)
    #pragma unroll
    for (int p = 0; p < 8; ++p) {
        int r = wid * 16 + p * 2;
        const unsigned short* gb = Wb + (size_t)(bn + r) * F + lane * 8;
        __builtin_amdgcn_global_load_lds(
            (const __attribute__((address_space(1))) unsigned int*)gb,
            (__attribute__((address_space(3))) unsigned int*)&sB[r * F],
            16, 0, 0);
    }

    // bias fragment (n-mapping fixed per thread)
    float bias[4];
    #pragma unroll
    for (int nt = 0; nt < 4; ++nt) {
        int n = bn + nt * 16 + l15;
        bias[nt] = (n < F) ? b1v[n] : 0.f;
    }

    auto stageA = [&](int buf, int bm_, int k0) {
        #pragma unroll
        for (int p = 0; p < 4; ++p) {
            int r = wid * 32 + p * 8;
            int am = bm_ + r + st_r; if (am > M - 1) am = M - 1;   // clamp; stores guarded
            const unsigned short* ga = hb + (size_t)am * F + k0 + st_k;
            __builtin_amdgcn_global_load_lds(
                (const __attribute__((address_space(1))) unsigned int*)ga,
                (__attribute__((address_space(3))) unsigned int*)&sA[buf][r * BK],
                16, 0, 0);
        }
    };

    for (int it = 0; it < NITER; ++it) {
        const int strip = bxg * NITER + it;
        const int bm = strip * BM;
        if (bm >= M) break;

        float4v acc[2][4];
        #pragma unroll
        for (int i = 0; i < 2; ++i)
            #pragma unroll
            for (int j = 0; j < 4; ++j) acc[i][j] = (float4v)(0.f);

        stageA(0, bm, 0);          // prologue: tile 0 -> buf 0
        __syncthreads();           // drains tile0 (and sB on first strip)

        #pragma unroll
        for (int kt = 0; kt < 4; ++kt) {
            const int cur = kt & 1;
            if (kt < 3) stageA(cur ^ 1, bm, (kt + 1) * BK);   // issue next tile early

            #pragma unroll
            for (int ks = 0; ks < 2; ++ks) {
                const int koff = (ks * 32 + quad * 8 + rot) & 63;
                short8 afr[2], bfr[4];
                #pragma unroll
                for (int mt = 0; mt < 2; ++mt)
                    afr[mt] = *(const short8*)&sA[cur][(wid * 32 + mt * 16 + l15) * BK + koff];
                #pragma unroll
                for (int nt = 0; nt < 4; ++nt)
                    bfr[nt] = *(const short8*)&sB[(nt * 16 + l15) * F + kt * BK + koff];
                #pragma unroll
                for (int mt = 0; mt < 2; ++mt)
                    #pragma unroll
                    for (int nt = 0; nt < 4; ++nt)
                        acc[mt][nt] = __builtin_amdgcn_mfma_f32_16x16x32_bf16(
                            afr[mt], bfr[nt], acc[mt][nt], 0, 0, 0);
            }
            __syncthreads();   // drains next-tile loads; protects buffer swap
        }

        // epilogue: pack bf16 tile into sA[0], coalesced uint4 stores
        #pragma unroll
        for (int mt = 0; mt < 2; ++mt) {
            #pragma unroll
            for (int rr = 0; rr < 4; ++rr) {
                int row = wid * 32 + mt * 16 + quad * 4 + rr;
                #pragma unroll
                for (int nt = 0; nt < 4; ++nt)
                    sA[0][row * BK + nt * 16 + l15] = f2bf(acc[mt][nt][rr] + bias[nt]);
            }
        }
        __syncthreads();
        #pragma unroll
        for (int p = 0; p < 4; ++p) {
            int row = p * 32 + (tid >> 3);
            int gm = bm + row;
            if (gm < M) {
                uint4 v = *(const uint4*)&sA[0][row * BK + (tid & 7) * 8];
                *(uint4*)(C + (size_t)gm * TWO_F + bn + (tid & 7) * 8) = v;
            }
        }
        __syncthreads();   // protect sA[0] from next strip's staging
    }
}

// ---------- edge sort (counting sort by src bucket = src>>7) ----------
__global__ __launch_bounds__(256) void hist_kernel(
    const int* __restrict__ src, int* __restrict__ counts, int E)
{
    int i = blockIdx.x * 256 + threadIdx.x;
    if (i < E) atomicAdd(&counts[((unsigned)src[i]) >> 7], 1);
}

__global__ void scan_kernel(const int* __restrict__ counts, int* __restrict__ cursor)
{
    __shared__ int s[512];
    int tid = threadIdx.x;
    int v = (tid < NBKT) ? counts[tid] : 0;
    s[tid] = v;
    __syncthreads();
    #pragma unroll
    for (int off = 1; off < 512; off <<= 1) {
        int x = (tid >= off) ? s[tid - off] : 0;
        __syncthreads();
        s[tid] += x;
        __syncthreads();
    }
    if (tid < NBKT) cursor[tid] = s[tid] - v;   // exclusive prefix
}

__global__ __launch_bounds__(256) void scatter_kernel(
    const int* __restrict__ src, const int* __restrict__ dst,
    int* __restrict__ cursor, int2* __restrict__ sort_sd,
    int* __restrict__ sort_idx, int E)
{
    int i = blockIdx.x * 256 + threadIdx.x;
    if (i < E) {
        int s = src[i];
        int pos = atomicAdd(&cursor[((unsigned)s) >> 7], 1);
        sort_sd[pos] = make_int2(s, dst[i]);
        sort_idx[pos] = i;
    }
}

// ---------- kernel 3: per-edge score over src-sorted edges, 2 edges per 32-lane group ----------
// XCD-contiguous block swizzle: each XCD walks a contiguous span of sorted edges -> each
// src bucket's rows (64KB) fetched once into that XCD's L2.
__global__ __launch_bounds__(256) void edge_kernel(
    const unsigned short* __restrict__ C,
    const int2* __restrict__ sd, const int* __restrict__ sidx,
    const float* __restrict__ w2,
    const float* __restrict__ b2, float* __restrict__ out, int E)
{
    const int lane = threadIdx.x & 31;
    const int nblk = gridDim.x;
    const int ib = blockIdx.x;
    const int gb = (nblk & 7) == 0 ? ((ib & 7) * (nblk >> 3) + (ib >> 3)) : ib;
    const int g = gb * 8 + (threadIdx.x >> 5);
    const int e0 = g * 2;
    if (e0 >= E) return;
    const bool has1 = (e0 + 1 < E);
    int2 p0 = sd[e0];
    int2 p1 = has1 ? sd[e0 + 1] : p0;
    int i0 = sidx[e0];
    int i1 = has1 ? sidx[e0 + 1] : 0;

    uint4 av0 = *(const uint4*)(C + (size_t)p0.x * TWO_F + lane * 8);
    uint4 bv0 = *(const uint4*)(C + (size_t)p0.y * TWO_F + F + lane * 8);
    uint4 av1 = *(const uint4*)(C + (size_t)p1.x * TWO_F + lane * 8);
    uint4 bv1 = *(const uint4*)(C + (size_t)p1.y * TWO_F + F + lane * 8);
    float4 w0 = *(const float4*)(w2 + lane * 8);
    float4 w1 = *(const float4*)(w2 + lane * 8 + 4);

    float sum0, sum1;
    sum0  = w0.x * fmaxf(blo(av0.x) + blo(bv0.x), 0.f);
    sum0 += w0.y * fmaxf(rawf(av0.x) + rawf(bv0.x), 0.f);
    sum0 += w0.z * fmaxf(blo(av0.y) + blo(bv0.y), 0.f);
    sum0 += w0.w * fmaxf(rawf(av0.y) + rawf(bv0.y), 0.f);
    sum0 += w1.x * fmaxf(blo(av0.z) + blo(bv0.z), 0.f);
    sum0 += w1.y * fmaxf(rawf(av0.z) + rawf(bv0.z), 0.f);
    sum0 += w1.z * fmaxf(blo(av0.w) + blo(bv0.w), 0.f);
    sum0 += w1.w * fmaxf(rawf(av0.w) + rawf(bv0.w), 0.f);

    sum1  = w0.x * fmaxf(blo(av1.x) + blo(bv1.x), 0.f);
    sum1 += w0.y * fmaxf(rawf(av1.x) + rawf(bv1.x), 0.f);
    sum1 += w0.z * fmaxf(blo(av1.y) + blo(bv1.y), 0.f);
    sum1 += w0.w * fmaxf(rawf(av1.y) + rawf(bv1.y), 0.f);
    sum1 += w1.x * fmaxf(blo(av1.z) + blo(bv1.z), 0.f);
    sum1 += w1.y * fmaxf(rawf(av1.z) + rawf(bv1.z), 0.f);
    sum1 += w1.z * fmaxf(blo(av1.w) + blo(bv1.w), 0.f);
    sum1 += w1.w * fmaxf(rawf(av1.w) + rawf(bv1.w), 0.f);

    #pragma unroll
    for (int off = 16; off > 0; off >>= 1) {
        sum0 += __shfl_down(sum0, off, 32);
        sum1 += __shfl_down(sum1, off, 32);
    }

    if (lane == 0) {
        float b = b2[0];
        out[i0] = sum0 + b;
        if (has1) out[i1] = sum1 + b;
    }
}

extern "C" void kernel_launch(void* const* d_in, const int* in_sizes, int n_in,
                              void* d_out, int out_size, void* d_ws, size_t ws_size,
                              hipStream_t stream) {
    const float* h    = (const float*)d_in[0];
    const int*   src  = (const int*)d_in[1];
    const int*   dst  = (const int*)d_in[2];
    const float* W1_w = (const float*)d_in[3];
    const float* W1_b = (const float*)d_in[4];
    const float* W2_w = (const float*)d_in[5];
    const float* W2_b = (const float*)d_in[6];
    float* out = (float*)d_out;

    const int M = in_sizes[0] / F;   // 50000
    const int E = in_sizes[1];       // 800000

    // ws: [Wb 256KB][pad to 512KB][hb 25.6MB pad 26MB][C 51.2MB]
    // sort scratch overlays hb (dead after gemm): sd 6.4MB @+0, idx 3.2MB @+8MB,
    // counts/cursor @+12MB.
    unsigned short* Wb = (unsigned short*)d_ws;
    unsigned short* hb = (unsigned short*)((char*)d_ws + 512 * 1024);
    unsigned short* C  = (unsigned short*)((char*)d_ws + 512 * 1024 + 26 * 1024 * 1024);
    int2* sort_sd  = (int2*)hb;
    int*  sort_idx = (int*)((char*)hb + 8 * 1024 * 1024);
    int*  counts   = (int*)((char*)hb + 12 * 1024 * 1024);
    int*  cursor   = counts + 512;

    // merged prep
    int prep_threads = M * 128 > TWO_F * F ? M * 128 : TWO_F * F;
    prep_kernel<<<(prep_threads + 255) / 256, 256, 0, stream>>>(h, W1_w, hb, Wb, M);

    // gemm: 56 m-groups x 8 n-blocks
    gemm_kernel<<<56 * 8, 256, 0, stream>>>(hb, Wb, W1_b, C, M);

    // counting sort of edges by src bucket (after gemm: scratch overlays hb)
    hipMemsetAsync(counts, 0, 2 * 512 * sizeof(int), stream);
    hist_kernel<<<(E + 255) / 256, 256, 0, stream>>>(src, counts, E);
    scan_kernel<<<1, 512, 0, stream>>>(counts, cursor);
    scatter_kernel<<<(E + 255) / 256, 256, 0, stream>>>(src, dst, cursor, sort_sd, sort_idx, E);

    // edge scoring over sorted edges
    int eblocks = (E / 2 + 7) / 8;
    edge_kernel<<<eblocks, 256, 0, stream>>>(C, sort_sd, sort_idx, W2_w, W2_b, out, E);
}

// Round 4
// 243.204 us; speedup vs baseline: 3.1399x; 3.1399x over previous
//
#include <hip/hip_runtime.h>

#define F 256
#define TWO_F 512
#define BM 128
#define BN 64
#define BK 64
#define NBKT 512         // padded bucket count (real buckets: src>>7 -> 0..390)
#define EPB 4096         // edges per sort block (256 thr x 16)

typedef __attribute__((ext_vector_type(8))) short short8;
typedef __attribute__((ext_vector_type(4))) float float4v;

// ---------- bf16 helpers ----------
static __device__ __forceinline__ unsigned short f2bf(float f) {
    unsigned u = __float_as_uint(f);
    u += 0x7FFFu + ((u >> 16) & 1u);
    return (unsigned short)(u >> 16);
}
static __device__ __forceinline__ unsigned pack2(float lo, float hi) {
    unsigned a = __float_as_uint(lo) + 0x8000u;
    unsigned b = __float_as_uint(hi) + 0x8000u;
    return __builtin_amdgcn_perm(b, a, 0x07060302u);
}
static __device__ __forceinline__ float blo(unsigned u) { return __uint_as_float(u << 16); }
static __device__ __forceinline__ float rawf(unsigned u) { return __uint_as_float(u); }

// ---------- kernel 1 (merged prep): h fp32->hb bf16 and W1 fp32->Wb bf16, both k-rotated ----------
__global__ __launch_bounds__(256) void prep_kernel(
    const float* __restrict__ h, const float* __restrict__ W1,
    unsigned short* __restrict__ hb, unsigned short* __restrict__ Wb, int M)
{
    int i = blockIdx.x * blockDim.x + threadIdx.x;
    if (i < M * 128) {                       // h part: one bf16 pair per thread
        int m = i >> 7;
        int kp = (i & 127) * 2;
        float2 v = *(const float2*)(h + (size_t)m * F + kp);
        unsigned pk = pack2(v.x, v.y);
        int ksw = ((kp & 63) + (m & 7) * 8) & 63;
        *(unsigned*)(hb + (size_t)m * F + (kp & ~63) + ksw) = pk;
    }
    if (i < TWO_F * F) {                     // W part
        int n = i >> 8;
        int k = i & 255;
        float v = W1[(n & 255) * TWO_F + ((n >> 8) << 8) + k];
        int kin_sw = ((k & 63) + (n & 7) * 8) & 63;
        Wb[n * F + (k & ~63) + kin_sw] = f2bf(v);
    }
}

// ---------- kernel 2: C[m][n] = sum_k hb[m][k]*Wb[n][k] (+b1 for n<256), bf16 out ----------
// R2 structure (3136 blocks, XCD-paired) + double-buffered LDS stage-AHEAD:
// issue next K-tile's global_load_lds BEFORE computing current tile, so load latency hides
// under the 64 MFMAs; 4 barriers/block instead of 8. LDS 48KB -> 3 blocks/CU.
__global__ __launch_bounds__(256, 3) void gemm_kernel(
    const unsigned short* __restrict__ hb, const unsigned short* __restrict__ Wb,
    const float* __restrict__ b1v, unsigned short* __restrict__ C, int M)
{
    __shared__ unsigned short sA[2][BM * BK];   // 2 x 16 KB
    __shared__ unsigned short sB[2][BN * BK];   // 2 x  8 KB

    // XCD pairing: all 8 by-blocks of one bx share (ib&7) -> same XCD -> hb strip L2-reused 8x.
    const int ib = blockIdx.x;
    const int r8 = ib & 7;
    const int q  = ib >> 3;
    const int by = q & 7;
    const int bx = (q >> 3) * 8 + r8;
    const int bm = bx * BM;
    if (bm >= M) return;
    const int bn = by * BN;

    const int tid  = threadIdx.x;
    const int lane = tid & 63;
    const int wid  = tid >> 6;
    const int st_r = lane >> 3;
    const int st_k = (lane & 7) * 8;
    const int quad = lane >> 4;
    const int l15  = lane & 15;
    const int rot  = (l15 & 7) * 8;

    float4v acc[2][4];
    #pragma unroll
    for (int i = 0; i < 2; ++i)
        #pragma unroll
        for (int j = 0; j < 4; ++j) acc[i][j] = (float4v)(0.f);

    auto stage = [&](int buf, int k0) {
        #pragma unroll
        for (int p = 0; p < 4; ++p) {
            int r = wid * 32 + p * 8;
            int am = bm + r + st_r; if (am > M - 1) am = M - 1;   // clamp; stores guarded
            const unsigned short* ga = hb + (size_t)am * F + k0 + st_k;
            __builtin_amdgcn_global_load_lds(
                (const __attribute__((address_space(1))) unsigned int*)ga,
                (__attribute__((address_space(3))) unsigned int*)&sA[buf][r * BK],
                16, 0, 0);
        }
        #pragma unroll
        for (int p = 0; p < 2; ++p) {
            int r = wid * 16 + p * 8;
            const unsigned short* gb = Wb + (size_t)(bn + r + st_r) * F + k0 + st_k;
            __builtin_amdgcn_global_load_lds(
                (const __attribute__((address_space(1))) unsigned int*)gb,
                (__attribute__((address_space(3))) unsigned int*)&sB[buf][r * BK],
                16, 0, 0);
        }
    };

    stage(0, 0);   // prologue

    #pragma unroll
    for (int kt = 0; kt < 4; ++kt) {
        const int cur = kt & 1;
        __syncthreads();                        // cur buffers ready; prev buffers free
        if (kt < 3) stage(cur ^ 1, (kt + 1) * BK);   // in flight during compute below

        #pragma unroll
        for (int ks = 0; ks < 2; ++ks) {
            const int koff = (ks * 32 + quad * 8 + rot) & 63;
            short8 afr[2], bfr[4];
            #pragma unroll
            for (int mt = 0; mt < 2; ++mt)
                afr[mt] = *(const short8*)&sA[cur][(wid * 32 + mt * 16 + l15) * BK + koff];
            #pragma unroll
            for (int nt = 0; nt < 4; ++nt)
                bfr[nt] = *(const short8*)&sB[cur][(nt * 16 + l15) * BK + koff];
            #pragma unroll
            for (int mt = 0; mt < 2; ++mt)
                #pragma unroll
                for (int nt = 0; nt < 4; ++nt)
                    acc[mt][nt] = __builtin_amdgcn_mfma_f32_16x16x32_bf16(
                        afr[mt], bfr[nt], acc[mt][nt], 0, 0, 0);
        }
    }

    // epilogue: +b1 for the n<256 half, pack bf16 tile into sA[0], coalesced uint4 stores.
    // Safe: sA[0] was last *read* during kt=2 (all waves passed the kt=3 barrier since).
    float bias[4];
    #pragma unroll
    for (int nt = 0; nt < 4; ++nt) {
        int n = bn + nt * 16 + l15;
        bias[nt] = (n < F) ? b1v[n] : 0.f;
    }
    #pragma unroll
    for (int mt = 0; mt < 2; ++mt) {
        #pragma unroll
        for (int rr = 0; rr < 4; ++rr) {
            int row = wid * 32 + mt * 16 + quad * 4 + rr;
            #pragma unroll
            for (int nt = 0; nt < 4; ++nt)
                sA[0][row * BK + nt * 16 + l15] = f2bf(acc[mt][nt][rr] + bias[nt]);
        }
    }
    __syncthreads();
    #pragma unroll
    for (int p = 0; p < 4; ++p) {
        int row = p * 32 + (tid >> 3);
        int gm = bm + row;
        if (gm < M) {
            uint4 v = *(const uint4*)&sA[0][row * BK + (tid & 7) * 8];
            *(uint4*)(C + (size_t)gm * TWO_F + bn + (tid & 7) * 8) = v;
        }
    }
}

// ---------- edge sort: atomic-free 3-pass counting sort by src bucket (src>>7) ----------
// Pass A: per-block LDS histogram -> counts[block][bucket] via plain stores (no global atomics).
__global__ __launch_bounds__(256) void sort_count_kernel(
    const int* __restrict__ src, int* __restrict__ counts, int E)
{
    __shared__ int cnt[NBKT];
    const int tid = threadIdx.x;
    #pragma unroll
    for (int i = tid; i < NBKT; i += 256) cnt[i] = 0;
    __syncthreads();
    const int base = blockIdx.x * EPB;
    #pragma unroll
    for (int j = 0; j < EPB / 256; ++j) {
        int e = base + j * 256 + tid;
        if (e < E) atomicAdd(&cnt[((unsigned)src[e]) >> 7], 1);   // LDS atomic only
    }
    __syncthreads();
    #pragma unroll
    for (int i = tid; i < NBKT; i += 256) counts[blockIdx.x * NBKT + i] = cnt[i];
}

// Pass B: 1 block, 512 threads. Thread b: exclusive prefix of counts[*][b] across blocks
// (8-way unrolled so the independent loads pipeline), then LDS scan of bucket totals.
__global__ __launch_bounds__(512) void sort_scan_kernel(
    int* __restrict__ counts, int* __restrict__ bucketbase, int nsb)
{
    __shared__ int s[NBKT];
    const int tid = threadIdx.x;
    int run = 0;
    int blk = 0;
    for (; blk + 8 <= nsb; blk += 8) {
        int v[8];
        #pragma unroll
        for (int u = 0; u < 8; ++u) v[u] = counts[(blk + u) * NBKT + tid];
        #pragma unroll
        for (int u = 0; u < 8; ++u) { counts[(blk + u) * NBKT + tid] = run; run += v[u]; }
    }
    for (; blk < nsb; ++blk) {
        int v = counts[blk * NBKT + tid];
        counts[blk * NBKT + tid] = run;
        run += v;
    }
    s[tid] = run;                       // bucket total
    __syncthreads();
    #pragma unroll
    for (int off = 1; off < NBKT; off <<= 1) {
        int x = (tid >= off) ? s[tid - off] : 0;
        __syncthreads();
        s[tid] += x;
        __syncthreads();
    }
    bucketbase[tid] = s[tid] - run;     // exclusive prefix over buckets
}

// Pass C: scatter; rank within (block,bucket) from LDS atomics, position = bucketbase +
// per-block prefix + rank. No returning global atomics anywhere.
__global__ __launch_bounds__(256) void sort_scatter_kernel(
    const int* __restrict__ src, const int* __restrict__ dst,
    const int* __restrict__ counts, const int* __restrict__ bucketbase,
    int2* __restrict__ sort_sd, int* __restrict__ sort_idx, int E)
{
    __shared__ int cnt[NBKT];
    const int tid = threadIdx.x;
    #pragma unroll
    for (int i = tid; i < NBKT; i += 256) cnt[i] = 0;
    __syncthreads();
    const int base = blockIdx.x * EPB;
    #pragma unroll
    for (int j = 0; j < EPB / 256; ++j) {
        int e = base + j * 256 + tid;
        if (e < E) {
            int s = src[e];
            int b = ((unsigned)s) >> 7;
            int r = atomicAdd(&cnt[b], 1);                       // LDS atomic only
            int pos = bucketbase[b] + counts[blockIdx.x * NBKT + b] + r;
            sort_sd[pos] = make_int2(s, dst[e]);
            sort_idx[pos] = e;
        }
    }
}

// ---------- kernel 3: per-edge score over src-sorted edges, 2 edges per 32-lane group ----------
// XCD-contiguous swizzle: each XCD walks a contiguous span of sorted edges -> src rows
// near-sequential and L2/L1-resident (avg degree 16 -> consecutive groups share src rows).
__global__ __launch_bounds__(256) void edge_kernel(
    const unsigned short* __restrict__ C,
    const int2* __restrict__ sd, const int* __restrict__ sidx,
    const float* __restrict__ w2,
    const float* __restrict__ b2, float* __restrict__ out, int E)
{
    const int lane = threadIdx.x & 31;
    const int nblk = gridDim.x;
    const int ib = blockIdx.x;
    const int gb = (nblk & 7) == 0 ? ((ib & 7) * (nblk >> 3) + (ib >> 3)) : ib;
    const int g = gb * 8 + (threadIdx.x >> 5);
    const int e0 = g * 2;
    if (e0 >= E) return;
    const bool has1 = (e0 + 1 < E);
    int2 p0 = sd[e0];
    int2 p1 = has1 ? sd[e0 + 1] : p0;
    int i0 = sidx[e0];
    int i1 = has1 ? sidx[e0 + 1] : 0;

    uint4 av0 = *(const uint4*)(C + (size_t)p0.x * TWO_F + lane * 8);
    uint4 bv0 = *(const uint4*)(C + (size_t)p0.y * TWO_F + F + lane * 8);
    uint4 av1 = *(const uint4*)(C + (size_t)p1.x * TWO_F + lane * 8);
    uint4 bv1 = *(const uint4*)(C + (size_t)p1.y * TWO_F + F + lane * 8);
    float4 w0 = *(const float4*)(w2 + lane * 8);
    float4 w1 = *(const float4*)(w2 + lane * 8 + 4);

    float sum0, sum1;
    sum0  = w0.x * fmaxf(blo(av0.x) + blo(bv0.x), 0.f);
    sum0 += w0.y * fmaxf(rawf(av0.x) + rawf(bv0.x), 0.f);
    sum0 += w0.z * fmaxf(blo(av0.y) + blo(bv0.y), 0.f);
    sum0 += w0.w * fmaxf(rawf(av0.y) + rawf(bv0.y), 0.f);
    sum0 += w1.x * fmaxf(blo(av0.z) + blo(bv0.z), 0.f);
    sum0 += w1.y * fmaxf(rawf(av0.z) + rawf(bv0.z), 0.f);
    sum0 += w1.z * fmaxf(blo(av0.w) + blo(bv0.w), 0.f);
    sum0 += w1.w * fmaxf(rawf(av0.w) + rawf(bv0.w), 0.f);

    sum1  = w0.x * fmaxf(blo(av1.x) + blo(bv1.x), 0.f);
    sum1 += w0.y * fmaxf(rawf(av1.x) + rawf(bv1.x), 0.f);
    sum1 += w0.z * fmaxf(blo(av1.y) + blo(bv1.y), 0.f);
    sum1 += w0.w * fmaxf(rawf(av1.y) + rawf(bv1.y), 0.f);
    sum1 += w1.x * fmaxf(blo(av1.z) + blo(bv1.z), 0.f);
    sum1 += w1.y * fmaxf(rawf(av1.z) + rawf(bv1.z), 0.f);
    sum1 += w1.z * fmaxf(blo(av1.w) + blo(bv1.w), 0.f);
    sum1 += w1.w * fmaxf(rawf(av1.w) + rawf(bv1.w), 0.f);

    #pragma unroll
    for (int off = 16; off > 0; off >>= 1) {
        sum0 += __shfl_down(sum0, off, 32);
        sum1 += __shfl_down(sum1, off, 32);
    }

    if (lane == 0) {
        float b = b2[0];
        out[i0] = sum0 + b;
        if (has1) out[i1] = sum1 + b;
    }
}

extern "C" void kernel_launch(void* const* d_in, const int* in_sizes, int n_in,
                              void* d_out, int out_size, void* d_ws, size_t ws_size,
                              hipStream_t stream) {
    const float* h    = (const float*)d_in[0];
    const int*   src  = (const int*)d_in[1];
    const int*   dst  = (const int*)d_in[2];
    const float* W1_w = (const float*)d_in[3];
    const float* W1_b = (const float*)d_in[4];
    const float* W2_w = (const float*)d_in[5];
    const float* W2_b = (const float*)d_in[6];
    float* out = (float*)d_out;

    const int M = in_sizes[0] / F;   // 50000
    const int E = in_sizes[1];       // 800000

    // ws: [Wb 256KB][pad to 512KB][hb 25.6MB pad 26MB][C 51.2MB]
    // sort scratch overlays hb (dead after gemm): sd 6.4MB @+0, idx 3.2MB @+8MB,
    // counts 196*512*4=400KB @+12MB, bucketbase 2KB @+13MB.
    unsigned short* Wb = (unsigned short*)d_ws;
    unsigned short* hb = (unsigned short*)((char*)d_ws + 512 * 1024);
    unsigned short* C  = (unsigned short*)((char*)d_ws + 512 * 1024 + 26 * 1024 * 1024);
    int2* sort_sd    = (int2*)hb;
    int*  sort_idx   = (int*)((char*)hb + 8 * 1024 * 1024);
    int*  counts     = (int*)((char*)hb + 12 * 1024 * 1024);
    int*  bucketbase = (int*)((char*)hb + 13 * 1024 * 1024);

    // merged prep
    int prep_threads = M * 128 > TWO_F * F ? M * 128 : TWO_F * F;
    prep_kernel<<<(prep_threads + 255) / 256, 256, 0, stream>>>(h, W1_w, hb, Wb, M);

    // gemm: 392 m-chunks x 8 n-blocks, XCD-paired encoding (R2 grid)
    int nbx = ((M + BM - 1) / BM + 7) / 8 * 8;     // 392
    gemm_kernel<<<nbx * 8, 256, 0, stream>>>(hb, Wb, W1_b, C, M);

    // atomic-free counting sort by src bucket (scratch overlays hb after gemm)
    int nsb = (E + EPB - 1) / EPB;                 // 196
    sort_count_kernel<<<nsb, 256, 0, stream>>>(src, counts, E);
    sort_scan_kernel<<<1, 512, 0, stream>>>(counts, bucketbase, nsb);
    sort_scatter_kernel<<<nsb, 256, 0, stream>>>(src, dst, counts, bucketbase, sort_sd, sort_idx, E);

    // edge scoring over sorted edges
    int eblocks = (E / 2 + 7) / 8;                 // 50000
    edge_kernel<<<eblocks, 256, 0, stream>>>(C, sort_sd, sort_idx, W2_w, W2_b, out, E);
}